// Round 1
// baseline (491.470 us; speedup 1.0000x reference)
//
#include <hip/hip_runtime.h>
#include <hip/hip_bf16.h>

#define N_B 8
#define CH 256
#define HW 2304           // 48*48
#define SZ_QS (2304LL*2304LL)
#define SCALE 0.0390625f  // 10/256
#define EPSC 0.999999f

typedef __attribute__((ext_vector_type(8))) short bf8_t;
typedef __attribute__((ext_vector_type(4))) float f32x4;

// output offsets in floats
#define O1 0LL
#define O2 42467328LL
#define O3 84934656LL
#define O4 87588864LL
#define O5 90243072LL
#define O6 132710400LL

// ---------------------------------------------------------------------------
// K0: transpose+convert fp32 [n][c][hw] -> bf16 [n][hw][c]
// ---------------------------------------------------------------------------
__global__ __launch_bounds__(256) void k_tr(const float* __restrict__ q_in,
                                            const float* __restrict__ m_in,
                                            __hip_bfloat16* __restrict__ Abf,
                                            __hip_bfloat16* __restrict__ Bbf) {
  __shared__ float lds[64 * 65];
  const int n = blockIdx.z >> 1, which = blockIdx.z & 1;
  const float* src = which ? m_in : q_in;
  __hip_bfloat16* dst = which ? Bbf : Abf;
  const int q0 = blockIdx.x * 64, c0 = blockIdx.y * 64;
  const int tx = threadIdx.x & 63, ty = threadIdx.x >> 6;
#pragma unroll
  for (int p = 0; p < 16; ++p) {
    const int cl = p * 4 + ty;
    lds[cl * 65 + tx] = src[((size_t)n * CH + c0 + cl) * HW + q0 + tx];
  }
  __syncthreads();
#pragma unroll
  for (int p = 0; p < 16; ++p) {
    const int ql = p * 4 + ty;
    dst[((size_t)n * HW + q0 + ql) * CH + c0 + tx] = __float2bfloat16(lds[tx * 65 + ql]);
  }
}

// ---------------------------------------------------------------------------
// K1: bf16 MFMA GEMM, 128x128 tile, K=256.  out1 <- exp(SCALE * A.B^T)
// A = [n][q][k] bf16, B = [n][s][k] bf16 (both k-contiguous)
// ---------------------------------------------------------------------------
__global__ __launch_bounds__(256) void k_gemm(const unsigned short* __restrict__ Abf,
                                              const unsigned short* __restrict__ Bbf,
                                              float* __restrict__ out1) {
  __shared__ unsigned short lA[128 * 64];
  __shared__ unsigned short lB[128 * 64];
  const int n = blockIdx.z;
  const int s0 = blockIdx.x * 128, q0 = blockIdx.y * 128;
  const int t = threadIdx.x, l = t & 63, w = t >> 6;
  const int wm = w >> 1, wn = w & 1;

  f32x4 acc[4][4];
#pragma unroll
  for (int mi = 0; mi < 4; ++mi)
#pragma unroll
    for (int ni = 0; ni < 4; ++ni) {
      f32x4 z = {0.f, 0.f, 0.f, 0.f};
      acc[mi][ni] = z;
    }

  const size_t baseA = ((size_t)n * HW + q0) * CH;
  const size_t baseB = ((size_t)n * HW + s0) * CH;
  const int jj = t & 7;   // k-slot (8 bf16 each), coalesced on global side
  const int rr = t >> 3;  // row 0..31 per i-step

  for (int kc = 0; kc < 4; ++kc) {
    const int k0 = kc * 64;
#pragma unroll
    for (int i = 0; i < 4; ++i) {
      const int r = i * 32 + rr;
      bf8_t va = *(const bf8_t*)(Abf + baseA + (size_t)r * CH + k0 + jj * 8);
      bf8_t vb = *(const bf8_t*)(Bbf + baseB + (size_t)r * CH + k0 + jj * 8);
      // XOR swizzle on LDS write side; read side undoes it
      *(bf8_t*)(lA + r * 64 + ((jj ^ (r & 7)) * 8)) = va;
      *(bf8_t*)(lB + r * 64 + ((jj ^ (r & 7)) * 8)) = vb;
    }
    __syncthreads();
#pragma unroll
    for (int ks = 0; ks < 2; ++ks) {
      const int kb = ks * 4 + (l >> 4);
      bf8_t af[4], bfr[4];
#pragma unroll
      for (int mi = 0; mi < 4; ++mi) {
        const int r = wm * 64 + mi * 16 + (l & 15);
        af[mi] = *(const bf8_t*)(lA + r * 64 + ((kb ^ (r & 7)) * 8));
      }
#pragma unroll
      for (int ni = 0; ni < 4; ++ni) {
        const int r = wn * 64 + ni * 16 + (l & 15);
        bfr[ni] = *(const bf8_t*)(lB + r * 64 + ((kb ^ (r & 7)) * 8));
      }
#pragma unroll
      for (int mi = 0; mi < 4; ++mi)
#pragma unroll
        for (int ni = 0; ni < 4; ++ni)
          acc[mi][ni] = __builtin_amdgcn_mfma_f32_16x16x32_bf16(af[mi], bfr[ni], acc[mi][ni], 0, 0, 0);
    }
    __syncthreads();
  }

  // epilogue: e = exp(scale*acc).  C/D layout: col = l&15, row = (l>>4)*4 + reg
#pragma unroll
  for (int mi = 0; mi < 4; ++mi) {
    const int row = q0 + wm * 64 + mi * 16 + (l >> 4) * 4;
#pragma unroll
    for (int ni = 0; ni < 4; ++ni) {
      const int col = s0 + wn * 64 + ni * 16 + (l & 15);
      const size_t ob = ((size_t)n * HW + row) * HW + col;
#pragma unroll
      for (int r = 0; r < 4; ++r)
        out1[ob + (size_t)r * HW] = __expf(acc[mi][ni][r] * SCALE);
    }
  }
}

// ---------------------------------------------------------------------------
// K2: one pass over e -> colsum (direct-ish) + rowsum (wave reduce + atomics)
// grid (9, 24, 8), block 64.  memset sums to 0 first.
// ---------------------------------------------------------------------------
__global__ __launch_bounds__(64) void k_sums(const float* __restrict__ out1,
                                             float* __restrict__ rowsum,
                                             float* __restrict__ colsum) {
  const int n = blockIdx.z;
  const int s4 = blockIdx.x * 256 + threadIdx.x * 4;
  const int q0 = blockIdx.y * 96;
  const float* base = out1 + (size_t)n * SZ_QS;
  float c0 = 0.f, c1 = 0.f, c2 = 0.f, c3 = 0.f;
  for (int qi = 0; qi < 96; ++qi) {
    const int q = q0 + qi;
    const float4 v = *(const float4*)(base + (size_t)q * HW + s4);
    c0 += v.x; c1 += v.y; c2 += v.z; c3 += v.w;
    float rs = v.x + v.y + v.z + v.w;
#pragma unroll
    for (int m = 1; m < 64; m <<= 1) rs += __shfl_xor(rs, m, 64);
    if (threadIdx.x == 0) atomicAdd(&rowsum[n * HW + q], rs);
  }
  atomicAdd(&colsum[n * HW + s4 + 0], c0);
  atomicAdd(&colsum[n * HW + s4 + 1], c1);
  atomicAdd(&colsum[n * HW + s4 + 2], c2);
  atomicAdd(&colsum[n * HW + s4 + 3], c3);
}

__global__ __launch_bounds__(256) void k_inv(const float* __restrict__ s,
                                             float* __restrict__ inv) {
  const int i = blockIdx.x * 256 + threadIdx.x;
  inv[i] = 1.0f / s[i];
}

// ---------------------------------------------------------------------------
// K3: fused main pass.  Block = (n, h-band of 192 q, 128-wide s tile).
// Reads e once; writes instance (in place), tmp_instance, instance_d,
// and query/tmp_query via LDS transpose (48-q chunks).
// ---------------------------------------------------------------------------
__global__ __launch_bounds__(128) void k_main(float* __restrict__ out1,
                                              float* __restrict__ out2,
                                              float* __restrict__ out3,
                                              float* __restrict__ out5,
                                              float* __restrict__ out6,
                                              const float* __restrict__ invr,
                                              const float* __restrict__ invc) {
  __shared__ float ldsT[128 * 49];  // [s_local][48 q + pad]
  const int n = blockIdx.z, h = blockIdx.y, s0 = blockIdx.x * 128;
  const int t = threadIdx.x;
  const int sg = s0 + t;
  const float icv = invc[n * HW + sg];
  const float* invr_n = invr + n * HW;
  float* e_base = out1 + (size_t)n * SZ_QS;
  const int Q0 = h * 192;

  float acc[12];
#pragma unroll
  for (int i = 0; i < 12; ++i) acc[i] = 0.f;

  for (int ph = 0; ph < 4; ++ph) {
#pragma unroll
    for (int wi = 0; wi < 12; ++wi) {
#pragma unroll
      for (int pw = 0; pw < 4; ++pw) {
        const int col = wi * 4 + pw;
        const int q = Q0 + ph * 48 + col;
        const size_t eoff = (size_t)q * HW + sg;
        const float e = e_base[eoff];
        const float pi = e * icv;
        e_base[eoff] = pi;  // instance_masks in place
        const size_t r5 = ((size_t)((n * 144 + h * 12 + wi) * 16 + (ph * 4 + pw))) * HW + sg;
        out5[r5] = pi;      // tmp_instance_masks_d (row remap)
        acc[wi] += pi;
        const float pq = e * invr_n[q];
        ldsT[t * 49 + col] = pq;
      }
    }
    // flush this ph-row (48 q) transposed: out2 / out6
    __syncthreads();
    const int qf0 = Q0 + ph * 48;
    const int u = t & 3, sB = t >> 2;
#pragma unroll
    for (int pass = 0; pass < 4; ++pass) {
      const int sl = pass * 32 + sB;
      const int sgl = s0 + sl;
      const int rs = sgl / 48, cs = sgl % 48;
      const int sp = (rs >> 2) * 12 + (cs >> 2);
      const int spp = (rs & 3) * 4 + (cs & 3);
      const size_t o2row = ((size_t)n * HW + sgl) * HW;
      const size_t o6row = (((size_t)n * 144 + sp) * 16 + spp) * HW;
#pragma unroll
      for (int k = 0; k < 3; ++k) {
        const int slot = u + k * 4;  // float4 slot 0..11
        float4 v;
        v.x = ldsT[sl * 49 + slot * 4 + 0];
        v.y = ldsT[sl * 49 + slot * 4 + 1];
        v.z = ldsT[sl * 49 + slot * 4 + 2];
        v.w = ldsT[sl * 49 + slot * 4 + 3];
        *(float4*)(out2 + o2row + qf0 + slot * 4) = v;  // query_masks
        *(float4*)(out6 + o6row + qf0 + slot * 4) = v;  // tmp_query_masks_d
      }
    }
    __syncthreads();
  }
#pragma unroll
  for (int wi = 0; wi < 12; ++wi)
    out3[((size_t)(n * 144 + h * 12 + wi)) * HW + sg] = fminf(acc[wi], EPSC);
}

// ---------------------------------------------------------------------------
// K4: query_masks_d = min(sum over 16 rows of tmp_query, eps)
// ---------------------------------------------------------------------------
__global__ __launch_bounds__(256) void k_qd(const float* __restrict__ out6,
                                            float* __restrict__ out4) {
  const int n = blockIdx.y, sp = blockIdx.x;
  const float* b6 = out6 + (((size_t)n * 144 + sp) * 16) * HW;
  float* b4 = out4 + ((size_t)n * 144 + sp) * HW;
  for (int i = 0; i < 9; ++i) {
    const int qq = i * 256 + threadIdx.x;
    float s = 0.f;
#pragma unroll
    for (int spp = 0; spp < 16; ++spp) s += b6[(size_t)spp * HW + qq];
    b4[qq] = fminf(s, EPSC);
  }
}

// ---------------------------------------------------------------------------
extern "C" void kernel_launch(void* const* d_in, const int* in_sizes, int n_in,
                              void* d_out, int out_size, void* d_ws, size_t ws_size,
                              hipStream_t stream) {
  const float* mask_f = (const float*)d_in[0];
  const float* query_f = (const float*)d_in[1];
  float* out = (float*)d_out;
  float* out1 = out + O1;
  float* out2 = out + O2;
  float* out3 = out + O3;
  float* out4 = out + O4;
  float* out5 = out + O5;
  float* out6 = out + O6;

  const size_t abytes = (size_t)N_B * HW * CH * 2;  // 9,437,184 per operand
  const size_t sbytes = (size_t)N_B * HW * 4;       // 73,728 per sum array
  const size_t need = 2 * abytes + 4 * sbytes;

  __hip_bfloat16 *Abf, *Bbf;
  float *sums, *invs;
  if (ws_size >= need) {
    char* base = (char*)d_ws;
    Abf = (__hip_bfloat16*)base;
    Bbf = (__hip_bfloat16*)(base + abytes);
    sums = (float*)(base + 2 * abytes);
    invs = (float*)(base + 2 * abytes + 2 * sbytes);
  } else {
    // fall back to carving scratch out of out3/out4 regions (safe by ordering:
    // Abf/Bbf consumed by k_gemm before k_main writes out3; sums/invs live in
    // the tail of out4, overwritten only by the final k_qd).
    Abf = (__hip_bfloat16*)out4;
    Bbf = (__hip_bfloat16*)out3;
    sums = (float*)((char*)out4 + abytes);
    invs = sums + 2 * (N_B * HW);
  }
  float* rowsum = sums;
  float* colsum = sums + N_B * HW;
  float* invr = invs;
  float* invc = invs + N_B * HW;

  hipMemsetAsync(sums, 0, 2 * sbytes, stream);
  k_tr<<<dim3(36, 4, 16), 256, 0, stream>>>(query_f, mask_f, Abf, Bbf);
  k_gemm<<<dim3(18, 18, 8), 256, 0, stream>>>((const unsigned short*)Abf,
                                              (const unsigned short*)Bbf, out1);
  k_sums<<<dim3(9, 24, 8), 64, 0, stream>>>(out1, rowsum, colsum);
  k_inv<<<dim3(144), 256, 0, stream>>>(sums, invs);
  k_main<<<dim3(18, 12, 8), 128, 0, stream>>>(out1, out2, out3, out5, out6, invr, invc);
  k_qd<<<dim3(144, 8), 256, 0, stream>>>(out6, out4);
}

// Round 2
// 336.994 us; speedup vs baseline: 1.4584x; 1.4584x over previous
//
#include <hip/hip_runtime.h>
#include <hip/hip_bf16.h>

#define N_B 8
#define CH 256
#define HW 2304           // 48*48
#define SZ_QS (2304LL*2304LL)
#define SCALE 0.0390625f  // 10/256
#define EPSC 0.999999f

typedef __attribute__((ext_vector_type(8))) short bf8_t;
typedef __attribute__((ext_vector_type(4))) float f32x4;

// output offsets in floats
#define O1 0LL
#define O2 42467328LL
#define O3 84934656LL
#define O4 87588864LL
#define O5 90243072LL
#define O6 132710400LL

// ---------------------------------------------------------------------------
// K0: transpose+convert fp32 [n][c][hw] -> bf16 [n][hw][c]
// ---------------------------------------------------------------------------
__global__ __launch_bounds__(256) void k_tr(const float* __restrict__ q_in,
                                            const float* __restrict__ m_in,
                                            __hip_bfloat16* __restrict__ Abf,
                                            __hip_bfloat16* __restrict__ Bbf) {
  __shared__ float lds[64 * 65];
  const int n = blockIdx.z >> 1, which = blockIdx.z & 1;
  const float* src = which ? m_in : q_in;
  __hip_bfloat16* dst = which ? Bbf : Abf;
  const int q0 = blockIdx.x * 64, c0 = blockIdx.y * 64;
  const int tx = threadIdx.x & 63, ty = threadIdx.x >> 6;
#pragma unroll
  for (int p = 0; p < 16; ++p) {
    const int cl = p * 4 + ty;
    lds[cl * 65 + tx] = src[((size_t)n * CH + c0 + cl) * HW + q0 + tx];
  }
  __syncthreads();
#pragma unroll
  for (int p = 0; p < 16; ++p) {
    const int ql = p * 4 + ty;
    dst[((size_t)n * HW + q0 + ql) * CH + c0 + tx] = __float2bfloat16(lds[tx * 65 + ql]);
  }
}

// ---------------------------------------------------------------------------
// K1: bf16 MFMA GEMM, 128x128 tile, K=256.  out1 <- exp(SCALE * A.B^T)
// ---------------------------------------------------------------------------
__global__ __launch_bounds__(256) void k_gemm(const unsigned short* __restrict__ Abf,
                                              const unsigned short* __restrict__ Bbf,
                                              float* __restrict__ out1) {
  __shared__ unsigned short lA[128 * 64];
  __shared__ unsigned short lB[128 * 64];
  const int n = blockIdx.z;
  const int s0 = blockIdx.x * 128, q0 = blockIdx.y * 128;
  const int t = threadIdx.x, l = t & 63, w = t >> 6;
  const int wm = w >> 1, wn = w & 1;

  f32x4 acc[4][4];
#pragma unroll
  for (int mi = 0; mi < 4; ++mi)
#pragma unroll
    for (int ni = 0; ni < 4; ++ni) {
      f32x4 z = {0.f, 0.f, 0.f, 0.f};
      acc[mi][ni] = z;
    }

  const size_t baseA = ((size_t)n * HW + q0) * CH;
  const size_t baseB = ((size_t)n * HW + s0) * CH;
  const int jj = t & 7;
  const int rr = t >> 3;

  for (int kc = 0; kc < 4; ++kc) {
    const int k0 = kc * 64;
#pragma unroll
    for (int i = 0; i < 4; ++i) {
      const int r = i * 32 + rr;
      bf8_t va = *(const bf8_t*)(Abf + baseA + (size_t)r * CH + k0 + jj * 8);
      bf8_t vb = *(const bf8_t*)(Bbf + baseB + (size_t)r * CH + k0 + jj * 8);
      *(bf8_t*)(lA + r * 64 + ((jj ^ (r & 7)) * 8)) = va;
      *(bf8_t*)(lB + r * 64 + ((jj ^ (r & 7)) * 8)) = vb;
    }
    __syncthreads();
#pragma unroll
    for (int ks = 0; ks < 2; ++ks) {
      const int kb = ks * 4 + (l >> 4);
      bf8_t af[4], bfr[4];
#pragma unroll
      for (int mi = 0; mi < 4; ++mi) {
        const int r = wm * 64 + mi * 16 + (l & 15);
        af[mi] = *(const bf8_t*)(lA + r * 64 + ((kb ^ (r & 7)) * 8));
      }
#pragma unroll
      for (int ni = 0; ni < 4; ++ni) {
        const int r = wn * 64 + ni * 16 + (l & 15);
        bfr[ni] = *(const bf8_t*)(lB + r * 64 + ((kb ^ (r & 7)) * 8));
      }
#pragma unroll
      for (int mi = 0; mi < 4; ++mi)
#pragma unroll
        for (int ni = 0; ni < 4; ++ni)
          acc[mi][ni] = __builtin_amdgcn_mfma_f32_16x16x32_bf16(af[mi], bfr[ni], acc[mi][ni], 0, 0, 0);
    }
    __syncthreads();
  }

#pragma unroll
  for (int mi = 0; mi < 4; ++mi) {
    const int row = q0 + wm * 64 + mi * 16 + (l >> 4) * 4;
#pragma unroll
    for (int ni = 0; ni < 4; ++ni) {
      const int col = s0 + wn * 64 + ni * 16 + (l & 15);
      const size_t ob = ((size_t)n * HW + row) * HW + col;
#pragma unroll
      for (int r = 0; r < 4; ++r)
        out1[ob + (size_t)r * HW] = __expf(acc[mi][ni][r] * SCALE);
    }
  }
}

// ---------------------------------------------------------------------------
// zero the sum buffers (own kernel; hipMemsetAsync's fill node was suspect)
// ---------------------------------------------------------------------------
__global__ __launch_bounds__(256) void k_zero(float* __restrict__ p) {
  const int i = (blockIdx.x * 256 + threadIdx.x) * 4;
  *(float4*)(p + i) = make_float4(0.f, 0.f, 0.f, 0.f);
}

// ---------------------------------------------------------------------------
// K2: one pass over e -> colsum + rowsum (atomics into zeroed buffers).
// 256-thread blocks (4 waves x 48 rows), 4-row unroll for ILP.
// grid (9, 12, 8)
// ---------------------------------------------------------------------------
__global__ __launch_bounds__(256) void k_sums(const float* __restrict__ out1,
                                              float* __restrict__ rowsum,
                                              float* __restrict__ colsum) {
  const int n = blockIdx.z;
  const int lane = threadIdx.x & 63, w = threadIdx.x >> 6;
  const int s4 = blockIdx.x * 256 + lane * 4;
  const int q0 = blockIdx.y * 192 + w * 48;
  const float* base = out1 + (size_t)n * SZ_QS;
  float c0 = 0.f, c1 = 0.f, c2 = 0.f, c3 = 0.f;
  for (int qi = 0; qi < 48; qi += 4) {
    const float4 v0 = *(const float4*)(base + (size_t)(q0 + qi + 0) * HW + s4);
    const float4 v1 = *(const float4*)(base + (size_t)(q0 + qi + 1) * HW + s4);
    const float4 v2 = *(const float4*)(base + (size_t)(q0 + qi + 2) * HW + s4);
    const float4 v3 = *(const float4*)(base + (size_t)(q0 + qi + 3) * HW + s4);
    c0 += v0.x + v1.x + v2.x + v3.x;
    c1 += v0.y + v1.y + v2.y + v3.y;
    c2 += v0.z + v1.z + v2.z + v3.z;
    c3 += v0.w + v1.w + v2.w + v3.w;
    float r0 = v0.x + v0.y + v0.z + v0.w;
    float r1 = v1.x + v1.y + v1.z + v1.w;
    float r2 = v2.x + v2.y + v2.z + v2.w;
    float r3 = v3.x + v3.y + v3.z + v3.w;
#pragma unroll
    for (int m = 1; m < 64; m <<= 1) {
      r0 += __shfl_xor(r0, m, 64);
      r1 += __shfl_xor(r1, m, 64);
      r2 += __shfl_xor(r2, m, 64);
      r3 += __shfl_xor(r3, m, 64);
    }
    if (lane == 0) {
      atomicAdd(&rowsum[n * HW + q0 + qi + 0], r0);
      atomicAdd(&rowsum[n * HW + q0 + qi + 1], r1);
      atomicAdd(&rowsum[n * HW + q0 + qi + 2], r2);
      atomicAdd(&rowsum[n * HW + q0 + qi + 3], r3);
    }
  }
  atomicAdd(&colsum[n * HW + s4 + 0], c0);
  atomicAdd(&colsum[n * HW + s4 + 1], c1);
  atomicAdd(&colsum[n * HW + s4 + 2], c2);
  atomicAdd(&colsum[n * HW + s4 + 3], c3);
}

__global__ __launch_bounds__(256) void k_inv(const float* __restrict__ s,
                                             float* __restrict__ inv) {
  const int i = blockIdx.x * 256 + threadIdx.x;
  inv[i] = 1.0f / s[i];
}

// ---------------------------------------------------------------------------
// K3: fused main pass.  Block = (s-band of 192 = 4 spatial rows = 12 patches,
// q-band of 192, n).  Reads e once; writes instance (in place), tmp_instance,
// instance_d, query/tmp_query via LDS transpose, and (do_qd) query_masks_d
// straight from the LDS tile.
// ---------------------------------------------------------------------------
__global__ __launch_bounds__(192) void k_main(float* __restrict__ out1,
                                              float* __restrict__ out2,
                                              float* __restrict__ out3,
                                              float* __restrict__ out4,
                                              float* __restrict__ out5,
                                              float* __restrict__ out6,
                                              const float* __restrict__ invr,
                                              const float* __restrict__ invc,
                                              const int do_qd) {
  __shared__ float ldsT[192 * 49];  // [s_local][48 q + pad]
  const int n = blockIdx.z, h = blockIdx.y, sb = blockIdx.x;
  const int S0 = sb * 192;
  const int t = threadIdx.x;
  const int sg = S0 + t;
  const float icv = invc[n * HW + sg];
  const float* invr_n = invr + n * HW;
  float* e_base = out1 + (size_t)n * SZ_QS;
  const int Q0 = h * 192;

  float acc[12];
#pragma unroll
  for (int i = 0; i < 12; ++i) acc[i] = 0.f;

  for (int ph = 0; ph < 4; ++ph) {
    const int qf0 = Q0 + ph * 48;
#pragma unroll
    for (int wi = 0; wi < 12; ++wi) {
#pragma unroll
      for (int pw = 0; pw < 4; ++pw) {
        const int col = wi * 4 + pw;
        const int q = qf0 + col;
        const size_t eoff = (size_t)q * HW + sg;
        const float e = e_base[eoff];
        const float pi = e * icv;
        e_base[eoff] = pi;  // instance_masks in place
        out5[((size_t)((n * 144 + h * 12 + wi) * 16 + (ph * 4 + pw))) * HW + sg] = pi;
        acc[wi] += pi;
        ldsT[t * 49 + col] = e * invr_n[q];  // query_masks value
      }
    }
    __syncthreads();
    // flush this ph-row (48 q) transposed: out2 / out6
    const int u = t & 3, sB = t >> 2;
#pragma unroll
    for (int pass = 0; pass < 4; ++pass) {
      const int sl = pass * 48 + sB;
      const int sgl = S0 + sl;
      const int rs_ = sgl / 48, cs = sgl % 48;
      const int sp = (rs_ >> 2) * 12 + (cs >> 2);
      const int spp = (rs_ & 3) * 4 + (cs & 3);
      const size_t o2row = ((size_t)n * HW + sgl) * HW + qf0;
      const size_t o6row = (((size_t)n * 144 + sp) * 16 + spp) * HW + qf0;
#pragma unroll
      for (int k = 0; k < 3; ++k) {
        const int slot = u + k * 4;
        float4 v;
        v.x = ldsT[sl * 49 + slot * 4 + 0];
        v.y = ldsT[sl * 49 + slot * 4 + 1];
        v.z = ldsT[sl * 49 + slot * 4 + 2];
        v.w = ldsT[sl * 49 + slot * 4 + 3];
        *(float4*)(out2 + o2row + slot * 4) = v;  // query_masks
        *(float4*)(out6 + o6row + slot * 4) = v;  // tmp_query_masks_d
      }
    }
    if (do_qd) {
      // query_masks_d for the 12 s-patches of this block, 48 q of this ph
#pragma unroll
      for (int j = 0; j < 3; ++j) {
        const int idx = t + j * 192;     // 0..575
        const int cp = idx / 48;         // patch col 0..11
        const int ql = idx % 48;
        float ssum = 0.f;
#pragma unroll
        for (int rl = 0; rl < 4; ++rl)
#pragma unroll
          for (int cc = 0; cc < 4; ++cc)
            ssum += ldsT[(rl * 48 + cp * 4 + cc) * 49 + ql];
        out4[((size_t)(n * 144 + sb * 12 + cp)) * HW + qf0 + ql] = fminf(ssum, EPSC);
      }
    }
    __syncthreads();
  }
#pragma unroll
  for (int wi = 0; wi < 12; ++wi)
    out3[((size_t)(n * 144 + h * 12 + wi)) * HW + sg] = fminf(acc[wi], EPSC);
}

// ---------------------------------------------------------------------------
// K4 (fallback only): query_masks_d = min(sum over 16 rows of tmp_query, eps)
// ---------------------------------------------------------------------------
__global__ __launch_bounds__(256) void k_qd(const float* __restrict__ out6,
                                            float* __restrict__ out4) {
  const int n = blockIdx.y, sp = blockIdx.x;
  const float* b6 = out6 + (((size_t)n * 144 + sp) * 16) * HW;
  float* b4 = out4 + ((size_t)n * 144 + sp) * HW;
  for (int i = 0; i < 9; ++i) {
    const int qq = i * 256 + threadIdx.x;
    float s = 0.f;
#pragma unroll
    for (int spp = 0; spp < 16; ++spp) s += b6[(size_t)spp * HW + qq];
    b4[qq] = fminf(s, EPSC);
  }
}

// ---------------------------------------------------------------------------
extern "C" void kernel_launch(void* const* d_in, const int* in_sizes, int n_in,
                              void* d_out, int out_size, void* d_ws, size_t ws_size,
                              hipStream_t stream) {
  const float* mask_f = (const float*)d_in[0];
  const float* query_f = (const float*)d_in[1];
  float* out = (float*)d_out;
  float* out1 = out + O1;
  float* out2 = out + O2;
  float* out3 = out + O3;
  float* out4 = out + O4;
  float* out5 = out + O5;
  float* out6 = out + O6;

  const size_t abytes = (size_t)N_B * HW * CH * 2;  // 9,437,184 per operand
  const size_t sbytes = (size_t)N_B * HW * 4;       // 73,728 per sum array
  const size_t need = 2 * abytes + 4 * sbytes;

  __hip_bfloat16 *Abf, *Bbf;
  float *sums, *invs;
  int ws_ok;
  if (ws_size >= need) {
    ws_ok = 1;
    char* base = (char*)d_ws;
    Abf = (__hip_bfloat16*)base;
    Bbf = (__hip_bfloat16*)(base + abytes);
    sums = (float*)(base + 2 * abytes);
    invs = (float*)(base + 2 * abytes + 2 * sbytes);
  } else {
    // scratch carved from out regions; safe by kernel ordering. In this mode
    // k_main must NOT write out4 (invs live there) -> do_qd=0 + separate k_qd.
    ws_ok = 0;
    Abf = (__hip_bfloat16*)out4;
    Bbf = (__hip_bfloat16*)out3;
    sums = (float*)((char*)out4 + abytes);
    invs = sums + 2 * (N_B * HW);
  }
  float* rowsum = sums;
  float* colsum = sums + N_B * HW;
  float* invr = invs;
  float* invc = invs + N_B * HW;

  k_tr<<<dim3(36, 4, 16), 256, 0, stream>>>(query_f, mask_f, Abf, Bbf);
  k_gemm<<<dim3(18, 18, 8), 256, 0, stream>>>((const unsigned short*)Abf,
                                              (const unsigned short*)Bbf, out1);
  k_zero<<<dim3(36), 256, 0, stream>>>(sums);
  k_sums<<<dim3(9, 12, 8), 256, 0, stream>>>(out1, rowsum, colsum);
  k_inv<<<dim3(144), 256, 0, stream>>>(sums, invs);
  k_main<<<dim3(12, 12, 8), 192, 0, stream>>>(out1, out2, out3, out4, out5, out6,
                                              invr, invc, ws_ok);
  if (!ws_ok) k_qd<<<dim3(144, 8), 256, 0, stream>>>(out6, out4);
}

// Round 3
// 324.978 us; speedup vs baseline: 1.5123x; 1.0370x over previous
//
#include <hip/hip_runtime.h>
#include <hip/hip_bf16.h>

#define N_B 8
#define CH 256
#define HW 2304           // 48*48
#define SZ_QS (2304LL*2304LL)
#define SCALE 0.0390625f  // 10/256
#define EPSC 0.999999f

typedef __attribute__((ext_vector_type(8))) short bf8_t;
typedef __attribute__((ext_vector_type(4))) float f32x4;

// output offsets in floats
#define O1 0LL
#define O2 42467328LL
#define O3 84934656LL
#define O4 87588864LL
#define O5 90243072LL
#define O6 132710400LL

// ---------------------------------------------------------------------------
// K0: transpose+convert fp32 [n][c][hw] -> bf16 [n][hw][c]
// ---------------------------------------------------------------------------
__global__ __launch_bounds__(256) void k_tr(const float* __restrict__ q_in,
                                            const float* __restrict__ m_in,
                                            __hip_bfloat16* __restrict__ Abf,
                                            __hip_bfloat16* __restrict__ Bbf) {
  __shared__ float lds[64 * 65];
  const int n = blockIdx.z >> 1, which = blockIdx.z & 1;
  const float* src = which ? m_in : q_in;
  __hip_bfloat16* dst = which ? Bbf : Abf;
  const int q0 = blockIdx.x * 64, c0 = blockIdx.y * 64;
  const int tx = threadIdx.x & 63, ty = threadIdx.x >> 6;
#pragma unroll
  for (int p = 0; p < 16; ++p) {
    const int cl = p * 4 + ty;
    lds[cl * 65 + tx] = src[((size_t)n * CH + c0 + cl) * HW + q0 + tx];
  }
  __syncthreads();
#pragma unroll
  for (int p = 0; p < 16; ++p) {
    const int ql = p * 4 + ty;
    dst[((size_t)n * HW + q0 + ql) * CH + c0 + tx] = __float2bfloat16(lds[tx * 65 + ql]);
  }
}

// ---------------------------------------------------------------------------
// zero the sum buffers
// ---------------------------------------------------------------------------
__global__ __launch_bounds__(256) void k_zero(float* __restrict__ p) {
  const int i = (blockIdx.x * 256 + threadIdx.x) * 4;
  *(float4*)(p + i) = make_float4(0.f, 0.f, 0.f, 0.f);
}

// ---------------------------------------------------------------------------
// K1: bf16 MFMA GEMM, 128x128 tile, K=256.  out1 <- e = exp(SCALE * A.B^T)
// Epilogue also accumulates row/col sums of e via shuffle-reduce + atomics
// (replaces the former full re-read pass k_sums).
// ---------------------------------------------------------------------------
__global__ __launch_bounds__(256) void k_gemm(const unsigned short* __restrict__ Abf,
                                              const unsigned short* __restrict__ Bbf,
                                              float* __restrict__ out1,
                                              float* __restrict__ rowsum,
                                              float* __restrict__ colsum) {
  __shared__ unsigned short lA[128 * 64];
  __shared__ unsigned short lB[128 * 64];
  const int n = blockIdx.z;
  const int s0 = blockIdx.x * 128, q0 = blockIdx.y * 128;
  const int t = threadIdx.x, l = t & 63, w = t >> 6;
  const int wm = w >> 1, wn = w & 1;

  f32x4 acc[4][4];
#pragma unroll
  for (int mi = 0; mi < 4; ++mi)
#pragma unroll
    for (int ni = 0; ni < 4; ++ni) {
      f32x4 z = {0.f, 0.f, 0.f, 0.f};
      acc[mi][ni] = z;
    }

  const size_t baseA = ((size_t)n * HW + q0) * CH;
  const size_t baseB = ((size_t)n * HW + s0) * CH;
  const int jj = t & 7;
  const int rr = t >> 3;

  for (int kc = 0; kc < 4; ++kc) {
    const int k0 = kc * 64;
#pragma unroll
    for (int i = 0; i < 4; ++i) {
      const int r = i * 32 + rr;
      bf8_t va = *(const bf8_t*)(Abf + baseA + (size_t)r * CH + k0 + jj * 8);
      bf8_t vb = *(const bf8_t*)(Bbf + baseB + (size_t)r * CH + k0 + jj * 8);
      *(bf8_t*)(lA + r * 64 + ((jj ^ (r & 7)) * 8)) = va;
      *(bf8_t*)(lB + r * 64 + ((jj ^ (r & 7)) * 8)) = vb;
    }
    __syncthreads();
#pragma unroll
    for (int ks = 0; ks < 2; ++ks) {
      const int kb = ks * 4 + (l >> 4);
      bf8_t af[4], bfr[4];
#pragma unroll
      for (int mi = 0; mi < 4; ++mi) {
        const int r = wm * 64 + mi * 16 + (l & 15);
        af[mi] = *(const bf8_t*)(lA + r * 64 + ((kb ^ (r & 7)) * 8));
      }
#pragma unroll
      for (int ni = 0; ni < 4; ++ni) {
        const int r = wn * 64 + ni * 16 + (l & 15);
        bfr[ni] = *(const bf8_t*)(lB + r * 64 + ((kb ^ (r & 7)) * 8));
      }
#pragma unroll
      for (int mi = 0; mi < 4; ++mi)
#pragma unroll
        for (int ni = 0; ni < 4; ++ni)
          acc[mi][ni] = __builtin_amdgcn_mfma_f32_16x16x32_bf16(af[mi], bfr[ni], acc[mi][ni], 0, 0, 0);
    }
    __syncthreads();
  }

  // epilogue: e = exp(scale*acc); store + accumulate row/col partials.
  // C/D layout: col = l&15 (+ni*16+wn*64), row = (l>>4)*4 + r (+mi*16+wm*64)
  float rp[4][4];  // [mi][r] row partials (sum over this wave's 64 cols)
  float cp[4];     // [ni]    col partials (sum over this wave's 64 rows)
#pragma unroll
  for (int mi = 0; mi < 4; ++mi)
#pragma unroll
    for (int r = 0; r < 4; ++r) rp[mi][r] = 0.f;
#pragma unroll
  for (int ni = 0; ni < 4; ++ni) cp[ni] = 0.f;

#pragma unroll
  for (int mi = 0; mi < 4; ++mi) {
    const int row = q0 + wm * 64 + mi * 16 + (l >> 4) * 4;
#pragma unroll
    for (int ni = 0; ni < 4; ++ni) {
      const int col = s0 + wn * 64 + ni * 16 + (l & 15);
      const size_t ob = ((size_t)n * HW + row) * HW + col;
#pragma unroll
      for (int r = 0; r < 4; ++r) {
        const float e = __expf(acc[mi][ni][r] * SCALE);
        out1[ob + (size_t)r * HW] = e;
        rp[mi][r] += e;
        cp[ni] += e;
      }
    }
  }
  // row sums: reduce across the 16 col-lanes (l&15)
#pragma unroll
  for (int mi = 0; mi < 4; ++mi)
#pragma unroll
    for (int r = 0; r < 4; ++r) {
      float v = rp[mi][r];
      v += __shfl_xor(v, 1, 64);
      v += __shfl_xor(v, 2, 64);
      v += __shfl_xor(v, 4, 64);
      v += __shfl_xor(v, 8, 64);
      if ((l & 15) == 0)
        atomicAdd(&rowsum[n * HW + q0 + wm * 64 + mi * 16 + (l >> 4) * 4 + r], v);
    }
  // col sums: reduce across the 4 row-groups (l>>4)
#pragma unroll
  for (int ni = 0; ni < 4; ++ni) {
    float v = cp[ni];
    v += __shfl_xor(v, 16, 64);
    v += __shfl_xor(v, 32, 64);
    if (l < 16)
      atomicAdd(&colsum[n * HW + s0 + wn * 64 + ni * 16 + l], v);
  }
}

__global__ __launch_bounds__(256) void k_inv(const float* __restrict__ s,
                                             float* __restrict__ inv) {
  const int i = blockIdx.x * 256 + threadIdx.x;
  inv[i] = 1.0f / s[i];
}

// ---------------------------------------------------------------------------
// K3: fused main pass.  Block = (s-band of 192 = 4 spatial rows = 12 patches,
// q-band of 192, n).  Reads e once; writes instance (in place), tmp_instance,
// instance_d, query/tmp_query via LDS transpose, and (do_qd) query_masks_d
// straight from the LDS tile.
// ---------------------------------------------------------------------------
__global__ __launch_bounds__(192) void k_main(float* __restrict__ out1,
                                              float* __restrict__ out2,
                                              float* __restrict__ out3,
                                              float* __restrict__ out4,
                                              float* __restrict__ out5,
                                              float* __restrict__ out6,
                                              const float* __restrict__ invr,
                                              const float* __restrict__ invc,
                                              const int do_qd) {
  __shared__ float ldsT[192 * 49];  // [s_local][48 q + pad]
  const int n = blockIdx.z, h = blockIdx.y, sb = blockIdx.x;
  const int S0 = sb * 192;
  const int t = threadIdx.x;
  const int sg = S0 + t;
  const float icv = invc[n * HW + sg];
  const float* invr_n = invr + n * HW;
  float* e_base = out1 + (size_t)n * SZ_QS;
  const int Q0 = h * 192;

  float acc[12];
#pragma unroll
  for (int i = 0; i < 12; ++i) acc[i] = 0.f;

  for (int ph = 0; ph < 4; ++ph) {
    const int qf0 = Q0 + ph * 48;
#pragma unroll
    for (int wi = 0; wi < 12; ++wi) {
#pragma unroll
      for (int pw = 0; pw < 4; ++pw) {
        const int col = wi * 4 + pw;
        const int q = qf0 + col;
        const size_t eoff = (size_t)q * HW + sg;
        const float e = e_base[eoff];
        const float pi = e * icv;
        e_base[eoff] = pi;  // instance_masks in place
        out5[((size_t)((n * 144 + h * 12 + wi) * 16 + (ph * 4 + pw))) * HW + sg] = pi;
        acc[wi] += pi;
        ldsT[t * 49 + col] = e * invr_n[q];  // query_masks value
      }
    }
    __syncthreads();
    // flush this ph-row (48 q) transposed: out2 / out6
    const int u = t & 3, sB = t >> 2;
#pragma unroll
    for (int pass = 0; pass < 4; ++pass) {
      const int sl = pass * 48 + sB;
      const int sgl = S0 + sl;
      const int rs_ = sgl / 48, cs = sgl % 48;
      const int sp = (rs_ >> 2) * 12 + (cs >> 2);
      const int spp = (rs_ & 3) * 4 + (cs & 3);
      const size_t o2row = ((size_t)n * HW + sgl) * HW + qf0;
      const size_t o6row = (((size_t)n * 144 + sp) * 16 + spp) * HW + qf0;
#pragma unroll
      for (int k = 0; k < 3; ++k) {
        const int slot = u + k * 4;
        float4 v;
        v.x = ldsT[sl * 49 + slot * 4 + 0];
        v.y = ldsT[sl * 49 + slot * 4 + 1];
        v.z = ldsT[sl * 49 + slot * 4 + 2];
        v.w = ldsT[sl * 49 + slot * 4 + 3];
        *(float4*)(out2 + o2row + slot * 4) = v;  // query_masks
        *(float4*)(out6 + o6row + slot * 4) = v;  // tmp_query_masks_d
      }
    }
    if (do_qd) {
      // query_masks_d for the 12 s-patches of this block, 48 q of this ph
#pragma unroll
      for (int j = 0; j < 3; ++j) {
        const int idx = t + j * 192;     // 0..575
        const int cp_ = idx / 48;        // patch col 0..11
        const int ql = idx % 48;
        float ssum = 0.f;
#pragma unroll
        for (int rl = 0; rl < 4; ++rl)
#pragma unroll
          for (int cc = 0; cc < 4; ++cc)
            ssum += ldsT[(rl * 48 + cp_ * 4 + cc) * 49 + ql];
        out4[((size_t)(n * 144 + sb * 12 + cp_)) * HW + qf0 + ql] = fminf(ssum, EPSC);
      }
    }
    __syncthreads();
  }
#pragma unroll
  for (int wi = 0; wi < 12; ++wi)
    out3[((size_t)(n * 144 + h * 12 + wi)) * HW + sg] = fminf(acc[wi], EPSC);
}

// ---------------------------------------------------------------------------
// K4 (fallback only): query_masks_d = min(sum over 16 rows of tmp_query, eps)
// ---------------------------------------------------------------------------
__global__ __launch_bounds__(256) void k_qd(const float* __restrict__ out6,
                                            float* __restrict__ out4) {
  const int n = blockIdx.y, sp = blockIdx.x;
  const float* b6 = out6 + (((size_t)n * 144 + sp) * 16) * HW;
  float* b4 = out4 + ((size_t)n * 144 + sp) * HW;
  for (int i = 0; i < 9; ++i) {
    const int qq = i * 256 + threadIdx.x;
    float s = 0.f;
#pragma unroll
    for (int spp = 0; spp < 16; ++spp) s += b6[(size_t)spp * HW + qq];
    b4[qq] = fminf(s, EPSC);
  }
}

// ---------------------------------------------------------------------------
extern "C" void kernel_launch(void* const* d_in, const int* in_sizes, int n_in,
                              void* d_out, int out_size, void* d_ws, size_t ws_size,
                              hipStream_t stream) {
  const float* mask_f = (const float*)d_in[0];
  const float* query_f = (const float*)d_in[1];
  float* out = (float*)d_out;
  float* out1 = out + O1;
  float* out2 = out + O2;
  float* out3 = out + O3;
  float* out4 = out + O4;
  float* out5 = out + O5;
  float* out6 = out + O6;

  const size_t abytes = (size_t)N_B * HW * CH * 2;  // 9,437,184 per operand
  const size_t sbytes = (size_t)N_B * HW * 4;       // 73,728 per sum array
  const size_t need = 2 * abytes + 4 * sbytes;

  __hip_bfloat16 *Abf, *Bbf;
  float *sums, *invs;
  int ws_ok;
  if (ws_size >= need) {
    ws_ok = 1;
    char* base = (char*)d_ws;
    Abf = (__hip_bfloat16*)base;
    Bbf = (__hip_bfloat16*)(base + abytes);
    sums = (float*)(base + 2 * abytes);
    invs = (float*)(base + 2 * abytes + 2 * sbytes);
  } else {
    // scratch carved from out regions; safe by kernel ordering. In this mode
    // k_main must NOT write out4 (invs live there) -> do_qd=0 + separate k_qd.
    ws_ok = 0;
    Abf = (__hip_bfloat16*)out4;
    Bbf = (__hip_bfloat16*)out3;
    sums = (float*)((char*)out4 + abytes);
    invs = sums + 2 * (N_B * HW);
  }
  float* rowsum = sums;
  float* colsum = sums + N_B * HW;
  float* invr = invs;
  float* invc = invs + N_B * HW;

  k_tr<<<dim3(36, 4, 16), 256, 0, stream>>>(query_f, mask_f, Abf, Bbf);
  k_zero<<<dim3(36), 256, 0, stream>>>(sums);
  k_gemm<<<dim3(18, 18, 8), 256, 0, stream>>>((const unsigned short*)Abf,
                                              (const unsigned short*)Bbf,
                                              out1, rowsum, colsum);
  k_inv<<<dim3(144), 256, 0, stream>>>(sums, invs);
  k_main<<<dim3(12, 12, 8), 192, 0, stream>>>(out1, out2, out3, out4, out5, out6,
                                              invr, invc, ws_ok);
  if (!ws_ok) k_qd<<<dim3(144, 8), 256, 0, stream>>>(out6, out4);
}

// Round 4
// 315.005 us; speedup vs baseline: 1.5602x; 1.0317x over previous
//
#include <hip/hip_runtime.h>
#include <hip/hip_bf16.h>

#define N_B 8
#define CH 256
#define HW 2304           // 48*48
#define SZ_QS (2304LL*2304LL)
#define SCALE 0.0390625f  // 10/256
#define EPSC 0.999999f

typedef __attribute__((ext_vector_type(8))) short bf8_t;
typedef __attribute__((ext_vector_type(4))) float f32x4;

// output offsets in floats
#define O1 0LL
#define O2 42467328LL
#define O3 84934656LL
#define O4 87588864LL
#define O5 90243072LL
#define O6 132710400LL

// ---------------------------------------------------------------------------
// K0: transpose+convert fp32 [n][c][hw] -> bf16 [n][hw][c]
// ---------------------------------------------------------------------------
__global__ __launch_bounds__(256) void k_tr(const float* __restrict__ q_in,
                                            const float* __restrict__ m_in,
                                            __hip_bfloat16* __restrict__ Abf,
                                            __hip_bfloat16* __restrict__ Bbf) {
  __shared__ float lds[64 * 65];
  const int n = blockIdx.z >> 1, which = blockIdx.z & 1;
  const float* src = which ? m_in : q_in;
  __hip_bfloat16* dst = which ? Bbf : Abf;
  const int q0 = blockIdx.x * 64, c0 = blockIdx.y * 64;
  const int tx = threadIdx.x & 63, ty = threadIdx.x >> 6;
#pragma unroll
  for (int p = 0; p < 16; ++p) {
    const int cl = p * 4 + ty;
    lds[cl * 65 + tx] = src[((size_t)n * CH + c0 + cl) * HW + q0 + tx];
  }
  __syncthreads();
#pragma unroll
  for (int p = 0; p < 16; ++p) {
    const int ql = p * 4 + ty;
    dst[((size_t)n * HW + q0 + ql) * CH + c0 + tx] = __float2bfloat16(lds[tx * 65 + ql]);
  }
}

__global__ __launch_bounds__(256) void k_zero(float* __restrict__ p) {
  const int i = (blockIdx.x * 256 + threadIdx.x) * 4;
  *(float4*)(p + i) = make_float4(0.f, 0.f, 0.f, 0.f);
}

__global__ __launch_bounds__(256) void k_inv(const float* __restrict__ s,
                                             float* __restrict__ inv) {
  const int i = blockIdx.x * 256 + threadIdx.x;
  inv[i] = 1.0f / s[i];
}

// ---------------------------------------------------------------------------
// Fused GEMM, 192x192 tile, 8 waves (2 wm x 4 wn), K=256.
// FULL=0: epilogue reduces e=exp(SCALE*acc) into rowsum/colsum (atomics).
// FULL=1: epilogue writes out1..out6 directly from registers (+small LDS).
// ---------------------------------------------------------------------------
template <int FULL>
__global__ __launch_bounds__(512) void k_g192(
    const unsigned short* __restrict__ Abf, const unsigned short* __restrict__ Bbf,
    float* __restrict__ out1, float* __restrict__ out2, float* __restrict__ out3,
    float* __restrict__ out4, float* __restrict__ out5, float* __restrict__ out6,
    float* __restrict__ rowsum, float* __restrict__ colsum,
    const float* __restrict__ invr, const float* __restrict__ invc) {
  __shared__ char smem[49152];
  unsigned short* lA = (unsigned short*)smem;            // [192][64] bf16, 24576 B
  unsigned short* lB = (unsigned short*)(smem + 24576);  // [192][64] bf16, 24576 B

  const int n = blockIdx.z;
  const int S0 = blockIdx.x * 192, Q0 = blockIdx.y * 192;
  const int t = threadIdx.x, l = t & 63, w = t >> 6;
  const int wm = w >> 2, wn = w & 3;       // wave grid 2(m=96q) x 4(n=48s)
  const int g = l >> 4, c = l & 15;

  f32x4 acc[6][3];
#pragma unroll
  for (int mi = 0; mi < 6; ++mi)
#pragma unroll
    for (int ni = 0; ni < 3; ++ni) {
      f32x4 z = {0.f, 0.f, 0.f, 0.f};
      acc[mi][ni] = z;
    }

  const size_t baseA = ((size_t)n * HW + Q0) * CH;
  const size_t baseB = ((size_t)n * HW + S0) * CH;
  const int jj = t & 7;   // k-slot of 8 bf16
  const int rr = t >> 3;  // 0..63

  for (int kc = 0; kc < 4; ++kc) {
    const int k0 = kc * 64;
#pragma unroll
    for (int i = 0; i < 3; ++i) {
      const int r = i * 64 + rr;
      bf8_t va = *(const bf8_t*)(Abf + baseA + (size_t)r * CH + k0 + jj * 8);
      bf8_t vb = *(const bf8_t*)(Bbf + baseB + (size_t)r * CH + k0 + jj * 8);
      *(bf8_t*)(lA + r * 64 + ((jj ^ (r & 7)) * 8)) = va;
      *(bf8_t*)(lB + r * 64 + ((jj ^ (r & 7)) * 8)) = vb;
    }
    __syncthreads();
#pragma unroll
    for (int ks = 0; ks < 2; ++ks) {
      const int kb = ks * 4 + g;
      bf8_t af[6], bf_[3];
#pragma unroll
      for (int mi = 0; mi < 6; ++mi) {
        const int r = wm * 96 + mi * 16 + c;
        af[mi] = *(const bf8_t*)(lA + r * 64 + ((kb ^ (r & 7)) * 8));
      }
#pragma unroll
      for (int ni = 0; ni < 3; ++ni) {
        const int r = wn * 48 + ni * 16 + c;
        bf_[ni] = *(const bf8_t*)(lB + r * 64 + ((kb ^ (r & 7)) * 8));
      }
#pragma unroll
      for (int mi = 0; mi < 6; ++mi)
#pragma unroll
        for (int ni = 0; ni < 3; ++ni)
          acc[mi][ni] = __builtin_amdgcn_mfma_f32_16x16x32_bf16(af[mi], bf_[ni], acc[mi][ni], 0, 0, 0);
    }
    __syncthreads();
  }

  // e = exp(SCALE*acc).  C/D layout: col(s) = c (+ni*16+wn*48), row(q) = g*4+r (+mi*16+wm*96)
#pragma unroll
  for (int mi = 0; mi < 6; ++mi)
#pragma unroll
    for (int ni = 0; ni < 3; ++ni)
#pragma unroll
      for (int r = 0; r < 4; ++r)
        acc[mi][ni][r] = __expf(acc[mi][ni][r] * SCALE);

  if (!FULL) {
    // row sums (over s) and col sums (over q)
#pragma unroll
    for (int mi = 0; mi < 6; ++mi)
#pragma unroll
      for (int r = 0; r < 4; ++r) {
        float v = acc[mi][0][r] + acc[mi][1][r] + acc[mi][2][r];
        v += __shfl_xor(v, 1, 64);
        v += __shfl_xor(v, 2, 64);
        v += __shfl_xor(v, 4, 64);
        v += __shfl_xor(v, 8, 64);
        if (c == 0) atomicAdd(&rowsum[n * HW + Q0 + wm * 96 + mi * 16 + g * 4 + r], v);
      }
#pragma unroll
    for (int ni = 0; ni < 3; ++ni) {
      float v = 0.f;
#pragma unroll
      for (int mi = 0; mi < 6; ++mi)
#pragma unroll
        for (int r = 0; r < 4; ++r) v += acc[mi][ni][r];
      v += __shfl_xor(v, 16, 64);
      v += __shfl_xor(v, 32, 64);
      if (g == 0) atomicAdd(&colsum[n * HW + S0 + wn * 48 + ni * 16 + c], v);
    }
    return;
  }

  // ---- FULL epilogue ----
  float icv[3];
#pragma unroll
  for (int ni = 0; ni < 3; ++ni) icv[ni] = invc[n * HW + S0 + wn * 48 + ni * 16 + c];

  // Phase A: out1/out5 (pi, scalar) + out2/out6 (pq, float4 along q)
#pragma unroll
  for (int mi = 0; mi < 6; ++mi) {
    const int qb = Q0 + wm * 96 + mi * 16 + g * 4;  // + r
    const f32x4 irv = *(const f32x4*)(invr + n * HW + qb);
#pragma unroll
    for (int ni = 0; ni < 3; ++ni) {
      const int s = S0 + wn * 48 + ni * 16 + c;
      const f32x4 pq = acc[mi][ni] * irv;
      const int rs_ = s / 48, cs = s % 48;
      const int sp = (rs_ >> 2) * 12 + (cs >> 2), spp = (rs_ & 3) * 4 + (cs & 3);
      *(f32x4*)(out2 + ((size_t)n * HW + s) * HW + qb) = pq;
      *(f32x4*)(out6 + (((size_t)n * 144 + sp) * 16 + spp) * HW + qb) = pq;
#pragma unroll
      for (int r = 0; r < 4; ++r) {
        const float pi = acc[mi][ni][r] * icv[ni];
        const int q = qb + r;
        const int hq = q / 192, rem = q % 192, ph = rem / 48, wi = (rem % 48) >> 2, pw = rem & 3;
        out1[((size_t)n * HW + q) * HW + s] = pi;
        out5[(((size_t)n * 144 + hq * 12 + wi) * 16 + ph * 4 + pw) * HW + s] = pi;
      }
    }
  }

  // Phase B: out3 (instance_d) — per-thread patch partials, combine wm halves in LDS
  float* buf3 = (float*)smem;  // [(wm*12 + b)*193 + sl], 18528 B
#pragma unroll
  for (int mi = 0; mi < 3; ++mi) {
    const int b = mi * 4 + g;  // q-patch col 0..11
#pragma unroll
    for (int ni = 0; ni < 3; ++ni) {
      const int sl = wn * 48 + ni * 16 + c;
      float p = 0.f;
#pragma unroll
      for (int r = 0; r < 4; ++r) p += acc[mi][ni][r] + acc[mi + 3][ni][r];
      buf3[(wm * 12 + b) * 193 + sl] = p * icv[ni];
    }
  }
  __syncthreads();
#pragma unroll
  for (int j = 0; j < 5; ++j) {
    const int idx = t + j * 512;
    if (idx < 2304) {
      const int b = idx / 192, sl = idx % 192;
      const float v = buf3[b * 193 + sl] + buf3[(12 + b) * 193 + sl];
      out3[((size_t)n * 144 + (Q0 / 192) * 12 + b) * HW + S0 + sl] = fminf(v, EPSC);
    }
  }
  __syncthreads();

  // Phase C: out4 (query_d) — shfl-reduce 4 s-lanes, combine 4 wn waves in LDS
  float* buf4 = (float*)smem;  // [(wn*12 + pc)*196 + qloc] float4, 37632 B
#pragma unroll
  for (int mi = 0; mi < 6; ++mi) {
    const int qloc = wm * 96 + mi * 16 + g * 4;
    const f32x4 irv = *(const f32x4*)(invr + n * HW + Q0 + qloc);
#pragma unroll
    for (int ni = 0; ni < 3; ++ni) {
      f32x4 pq = acc[mi][ni] * irv;
#pragma unroll
      for (int r = 0; r < 4; ++r) {
        pq[r] += __shfl_xor(pq[r], 1, 64);
        pq[r] += __shfl_xor(pq[r], 2, 64);
      }
      if ((c & 3) == 0) {
        const int pc = ni * 4 + (c >> 2);  // s-patch col 0..11
        *(f32x4*)(buf4 + (wn * 12 + pc) * 196 + qloc) = pq;
      }
    }
  }
  __syncthreads();
#pragma unroll
  for (int j = 0; j < 5; ++j) {
    const int idx = t + j * 512;
    if (idx < 2304) {
      const int pc = idx / 192, q = idx % 192;
      float v = buf4[pc * 196 + q] + buf4[(12 + pc) * 196 + q] +
                buf4[(24 + pc) * 196 + q] + buf4[(36 + pc) * 196 + q];
      out4[((size_t)n * 144 + (S0 / 192) * 12 + pc) * HW + Q0 + q] = fminf(v, EPSC);
    }
  }
}

// ===========================================================================
// Fallback path (ws too small): old validated kernels
// ===========================================================================
__global__ __launch_bounds__(256) void k_gemm_old(const unsigned short* __restrict__ Abf,
                                                  const unsigned short* __restrict__ Bbf,
                                                  float* __restrict__ out1,
                                                  float* __restrict__ rowsum,
                                                  float* __restrict__ colsum) {
  __shared__ unsigned short lA[128 * 64];
  __shared__ unsigned short lB[128 * 64];
  const int n = blockIdx.z;
  const int s0 = blockIdx.x * 128, q0 = blockIdx.y * 128;
  const int t = threadIdx.x, l = t & 63, w = t >> 6;
  const int wm = w >> 1, wn = w & 1;
  f32x4 acc[4][4];
#pragma unroll
  for (int mi = 0; mi < 4; ++mi)
#pragma unroll
    for (int ni = 0; ni < 4; ++ni) {
      f32x4 z = {0.f, 0.f, 0.f, 0.f};
      acc[mi][ni] = z;
    }
  const size_t baseA = ((size_t)n * HW + q0) * CH;
  const size_t baseB = ((size_t)n * HW + s0) * CH;
  const int jj = t & 7, rr = t >> 3;
  for (int kc = 0; kc < 4; ++kc) {
    const int k0 = kc * 64;
#pragma unroll
    for (int i = 0; i < 4; ++i) {
      const int r = i * 32 + rr;
      bf8_t va = *(const bf8_t*)(Abf + baseA + (size_t)r * CH + k0 + jj * 8);
      bf8_t vb = *(const bf8_t*)(Bbf + baseB + (size_t)r * CH + k0 + jj * 8);
      *(bf8_t*)(lA + r * 64 + ((jj ^ (r & 7)) * 8)) = va;
      *(bf8_t*)(lB + r * 64 + ((jj ^ (r & 7)) * 8)) = vb;
    }
    __syncthreads();
#pragma unroll
    for (int ks = 0; ks < 2; ++ks) {
      const int kb = ks * 4 + (l >> 4);
      bf8_t af[4], bfr[4];
#pragma unroll
      for (int mi = 0; mi < 4; ++mi) {
        const int r = wm * 64 + mi * 16 + (l & 15);
        af[mi] = *(const bf8_t*)(lA + r * 64 + ((kb ^ (r & 7)) * 8));
      }
#pragma unroll
      for (int ni = 0; ni < 4; ++ni) {
        const int r = wn * 64 + ni * 16 + (l & 15);
        bfr[ni] = *(const bf8_t*)(lB + r * 64 + ((kb ^ (r & 7)) * 8));
      }
#pragma unroll
      for (int mi = 0; mi < 4; ++mi)
#pragma unroll
        for (int ni = 0; ni < 4; ++ni)
          acc[mi][ni] = __builtin_amdgcn_mfma_f32_16x16x32_bf16(af[mi], bfr[ni], acc[mi][ni], 0, 0, 0);
    }
    __syncthreads();
  }
  float rp[4][4], cp[4];
#pragma unroll
  for (int mi = 0; mi < 4; ++mi)
#pragma unroll
    for (int r = 0; r < 4; ++r) rp[mi][r] = 0.f;
#pragma unroll
  for (int ni = 0; ni < 4; ++ni) cp[ni] = 0.f;
#pragma unroll
  for (int mi = 0; mi < 4; ++mi) {
    const int row = q0 + wm * 64 + mi * 16 + (l >> 4) * 4;
#pragma unroll
    for (int ni = 0; ni < 4; ++ni) {
      const int col = s0 + wn * 64 + ni * 16 + (l & 15);
      const size_t ob = ((size_t)n * HW + row) * HW + col;
#pragma unroll
      for (int r = 0; r < 4; ++r) {
        const float e = __expf(acc[mi][ni][r] * SCALE);
        out1[ob + (size_t)r * HW] = e;
        rp[mi][r] += e;
        cp[ni] += e;
      }
    }
  }
#pragma unroll
  for (int mi = 0; mi < 4; ++mi)
#pragma unroll
    for (int r = 0; r < 4; ++r) {
      float v = rp[mi][r];
      v += __shfl_xor(v, 1, 64);
      v += __shfl_xor(v, 2, 64);
      v += __shfl_xor(v, 4, 64);
      v += __shfl_xor(v, 8, 64);
      if ((l & 15) == 0)
        atomicAdd(&rowsum[n * HW + q0 + wm * 64 + mi * 16 + (l >> 4) * 4 + r], v);
    }
#pragma unroll
  for (int ni = 0; ni < 4; ++ni) {
    float v = cp[ni];
    v += __shfl_xor(v, 16, 64);
    v += __shfl_xor(v, 32, 64);
    if (l < 16) atomicAdd(&colsum[n * HW + s0 + wn * 64 + ni * 16 + l], v);
  }
}

__global__ __launch_bounds__(192) void k_main(float* __restrict__ out1,
                                              float* __restrict__ out2,
                                              float* __restrict__ out3,
                                              float* __restrict__ out5,
                                              float* __restrict__ out6,
                                              const float* __restrict__ invr,
                                              const float* __restrict__ invc) {
  __shared__ float ldsT[192 * 49];
  const int n = blockIdx.z, h = blockIdx.y, sb = blockIdx.x;
  const int S0 = sb * 192;
  const int t = threadIdx.x;
  const int sg = S0 + t;
  const float icv = invc[n * HW + sg];
  const float* invr_n = invr + n * HW;
  float* e_base = out1 + (size_t)n * SZ_QS;
  const int Q0 = h * 192;
  float acc[12];
#pragma unroll
  for (int i = 0; i < 12; ++i) acc[i] = 0.f;
  for (int ph = 0; ph < 4; ++ph) {
    const int qf0 = Q0 + ph * 48;
#pragma unroll
    for (int wi = 0; wi < 12; ++wi) {
#pragma unroll
      for (int pw = 0; pw < 4; ++pw) {
        const int col = wi * 4 + pw;
        const int q = qf0 + col;
        const size_t eoff = (size_t)q * HW + sg;
        const float e = e_base[eoff];
        const float pi = e * icv;
        e_base[eoff] = pi;
        out5[((size_t)((n * 144 + h * 12 + wi) * 16 + (ph * 4 + pw))) * HW + sg] = pi;
        acc[wi] += pi;
        ldsT[t * 49 + col] = e * invr_n[q];
      }
    }
    __syncthreads();
    const int u = t & 3, sB = t >> 2;
#pragma unroll
    for (int pass = 0; pass < 4; ++pass) {
      const int sl = pass * 48 + sB;
      const int sgl = S0 + sl;
      const int rs_ = sgl / 48, cs = sgl % 48;
      const int sp = (rs_ >> 2) * 12 + (cs >> 2);
      const int spp = (rs_ & 3) * 4 + (cs & 3);
      const size_t o2row = ((size_t)n * HW + sgl) * HW + qf0;
      const size_t o6row = (((size_t)n * 144 + sp) * 16 + spp) * HW + qf0;
#pragma unroll
      for (int k = 0; k < 3; ++k) {
        const int slot = u + k * 4;
        float4 v;
        v.x = ldsT[sl * 49 + slot * 4 + 0];
        v.y = ldsT[sl * 49 + slot * 4 + 1];
        v.z = ldsT[sl * 49 + slot * 4 + 2];
        v.w = ldsT[sl * 49 + slot * 4 + 3];
        *(float4*)(out2 + o2row + slot * 4) = v;
        *(float4*)(out6 + o6row + slot * 4) = v;
      }
    }
    __syncthreads();
  }
#pragma unroll
  for (int wi = 0; wi < 12; ++wi)
    out3[((size_t)(n * 144 + h * 12 + wi)) * HW + sg] = fminf(acc[wi], EPSC);
}

__global__ __launch_bounds__(256) void k_qd(const float* __restrict__ out6,
                                            float* __restrict__ out4) {
  const int n = blockIdx.y, sp = blockIdx.x;
  const float* b6 = out6 + (((size_t)n * 144 + sp) * 16) * HW;
  float* b4 = out4 + ((size_t)n * 144 + sp) * HW;
  for (int i = 0; i < 9; ++i) {
    const int qq = i * 256 + threadIdx.x;
    float s = 0.f;
#pragma unroll
    for (int spp = 0; spp < 16; ++spp) s += b6[(size_t)spp * HW + qq];
    b4[qq] = fminf(s, EPSC);
  }
}

// ---------------------------------------------------------------------------
extern "C" void kernel_launch(void* const* d_in, const int* in_sizes, int n_in,
                              void* d_out, int out_size, void* d_ws, size_t ws_size,
                              hipStream_t stream) {
  const float* mask_f = (const float*)d_in[0];
  const float* query_f = (const float*)d_in[1];
  float* out = (float*)d_out;
  float* out1 = out + O1;
  float* out2 = out + O2;
  float* out3 = out + O3;
  float* out4 = out + O4;
  float* out5 = out + O5;
  float* out6 = out + O6;

  const size_t abytes = (size_t)N_B * HW * CH * 2;  // 9,437,184 per operand
  const size_t sbytes = (size_t)N_B * HW * 4;       // 73,728 per sum array
  const size_t need = 2 * abytes + 4 * sbytes;

  if (ws_size >= need) {
    char* base = (char*)d_ws;
    __hip_bfloat16* Abf = (__hip_bfloat16*)base;
    __hip_bfloat16* Bbf = (__hip_bfloat16*)(base + abytes);
    float* sums = (float*)(base + 2 * abytes);
    float* invs = (float*)(base + 2 * abytes + 2 * sbytes);
    float* rowsum = sums;
    float* colsum = sums + N_B * HW;
    float* invr = invs;
    float* invc = invs + N_B * HW;

    k_tr<<<dim3(36, 4, 16), 256, 0, stream>>>(query_f, mask_f, Abf, Bbf);
    k_zero<<<dim3(36), 256, 0, stream>>>(sums);
    k_g192<0><<<dim3(12, 12, 8), 512, 0, stream>>>(
        (const unsigned short*)Abf, (const unsigned short*)Bbf,
        nullptr, nullptr, nullptr, nullptr, nullptr, nullptr,
        rowsum, colsum, nullptr, nullptr);
    k_inv<<<dim3(144), 256, 0, stream>>>(sums, invs);
    k_g192<1><<<dim3(12, 12, 8), 512, 0, stream>>>(
        (const unsigned short*)Abf, (const unsigned short*)Bbf,
        out1, out2, out3, out4, out5, out6,
        nullptr, nullptr, invr, invc);
  } else {
    // Fallback: scratch carved from out regions; old validated 3-kernel path.
    __hip_bfloat16* Abf = (__hip_bfloat16*)out4;
    __hip_bfloat16* Bbf = (__hip_bfloat16*)out3;
    float* sums = (float*)((char*)out4 + abytes);
    float* invs = sums + 2 * (N_B * HW);
    float* rowsum = sums;
    float* colsum = sums + N_B * HW;
    float* invr = invs;
    float* invc = invs + N_B * HW;

    k_tr<<<dim3(36, 4, 16), 256, 0, stream>>>(query_f, mask_f, Abf, Bbf);
    k_zero<<<dim3(36), 256, 0, stream>>>(sums);
    k_gemm_old<<<dim3(18, 18, 8), 256, 0, stream>>>(
        (const unsigned short*)Abf, (const unsigned short*)Bbf, out1, rowsum, colsum);
    k_inv<<<dim3(144), 256, 0, stream>>>(sums, invs);
    k_main<<<dim3(12, 12, 8), 192, 0, stream>>>(out1, out2, out3, out5, out6, invr, invc);
    k_qd<<<dim3(144, 8), 256, 0, stream>>>(out6, out4);
  }
}

// Round 5
// 243.151 us; speedup vs baseline: 2.0213x; 1.2955x over previous
//
#include <hip/hip_runtime.h>
#include <hip/hip_bf16.h>

#define N_B 8
#define CH 256
#define HW 2304           // 48*48
#define SZ_QS (2304LL*2304LL)
#define SCALE 0.0390625f  // 10/256
#define EPSC 0.999999f

typedef __attribute__((ext_vector_type(8))) short bf8_t;
typedef __attribute__((ext_vector_type(4))) float f32x4;

// output offsets in floats
#define O1 0LL
#define O2 42467328LL
#define O3 84934656LL
#define O4 87588864LL
#define O5 90243072LL
#define O6 132710400LL

// async global->LDS, 16B per lane, linear LDS dest (wave-uniform base + lane*16)
__device__ __forceinline__ void gl_lds16(const unsigned short* g, unsigned short* l) {
  __builtin_amdgcn_global_load_lds(
      (const __attribute__((address_space(1))) unsigned int*)g,
      (__attribute__((address_space(3))) unsigned int*)l, 16, 0, 0);
}

// ---------------------------------------------------------------------------
// K0: transpose+convert fp32 [n][c][hw] -> bf16 [n][hw][c]
// ---------------------------------------------------------------------------
__global__ __launch_bounds__(256) void k_tr(const float* __restrict__ q_in,
                                            const float* __restrict__ m_in,
                                            __hip_bfloat16* __restrict__ Abf,
                                            __hip_bfloat16* __restrict__ Bbf) {
  __shared__ float lds[64 * 65];
  const int n = blockIdx.z >> 1, which = blockIdx.z & 1;
  const float* src = which ? m_in : q_in;
  __hip_bfloat16* dst = which ? Bbf : Abf;
  const int q0 = blockIdx.x * 64, c0 = blockIdx.y * 64;
  const int tx = threadIdx.x & 63, ty = threadIdx.x >> 6;
#pragma unroll
  for (int p = 0; p < 16; ++p) {
    const int cl = p * 4 + ty;
    lds[cl * 65 + tx] = src[((size_t)n * CH + c0 + cl) * HW + q0 + tx];
  }
  __syncthreads();
#pragma unroll
  for (int p = 0; p < 16; ++p) {
    const int ql = p * 4 + ty;
    dst[((size_t)n * HW + q0 + ql) * CH + c0 + tx] = __float2bfloat16(lds[tx * 65 + ql]);
  }
}

__global__ __launch_bounds__(256) void k_zero(float* __restrict__ p) {
  const int i = (blockIdx.x * 256 + threadIdx.x) * 4;
  *(float4*)(p + i) = make_float4(0.f, 0.f, 0.f, 0.f);
}

__global__ __launch_bounds__(256) void k_inv(const float* __restrict__ s,
                                             float* __restrict__ inv) {
  const int i = blockIdx.x * 256 + threadIdx.x;
  inv[i] = 1.0f / s[i];
}

// ---------------------------------------------------------------------------
// Fused GEMM, 192x192 tile, 8 waves (2 wm x 4 wn), K=256.
// Staging: global_load_lds dwordx4, XOR swizzle baked into SOURCE address.
// FULL=0: epilogue reduces e=exp(SCALE*acc) into rowsum/colsum (atomics).
// FULL=1: epilogue streams pi/pq tiles through LDS, wide coalesced stores.
// ---------------------------------------------------------------------------
template <int FULL>
__global__ __launch_bounds__(512) void k_g192(
    const unsigned short* __restrict__ Abf, const unsigned short* __restrict__ Bbf,
    float* __restrict__ out1, float* __restrict__ out2, float* __restrict__ out3,
    float* __restrict__ out4, float* __restrict__ out5, float* __restrict__ out6,
    float* __restrict__ rowsum, float* __restrict__ colsum,
    const float* __restrict__ invr, const float* __restrict__ invc) {
  __shared__ char smem[49152];
  unsigned short* lA = (unsigned short*)smem;            // [192][64] bf16
  unsigned short* lB = (unsigned short*)(smem + 24576);  // [192][64] bf16

  const int n = blockIdx.z;
  const int S0 = blockIdx.x * 192, Q0 = blockIdx.y * 192;
  const int t = threadIdx.x, l = t & 63, w = t >> 6;
  const int wm = w >> 2, wn = w & 3;  // wave grid 2(m=96q) x 4(n=48s)
  const int g = l >> 4, c = l & 15;

  f32x4 acc[6][3];
#pragma unroll
  for (int mi = 0; mi < 6; ++mi)
#pragma unroll
    for (int ni = 0; ni < 3; ++ni) {
      f32x4 z = {0.f, 0.f, 0.f, 0.f};
      acc[mi][ni] = z;
    }

  // staging: wave w owns rows [w*24, w*24+24) of both A and B; 3 instrs each.
  // lane l -> (lrow=l>>3, lc8=l&7); source col swizzled so LDS[row][col8]
  // holds global[row][col8 ^ (row&7)] (row&7 == lrow since bases are 8-aligned)
  const int r0w = w * 24;
  const int lrow = l >> 3, lc8 = l & 7;
  const int scol = (lc8 ^ lrow) * 8;  // halves
  const unsigned short* gA = Abf + ((size_t)n * HW + Q0 + r0w + lrow) * CH + scol;
  const unsigned short* gB = Bbf + ((size_t)n * HW + S0 + r0w + lrow) * CH + scol;
  unsigned short* dA = lA + r0w * 64;
  unsigned short* dB = lB + r0w * 64;

  for (int kc = 0; kc < 4; ++kc) {
    const int k0 = kc * 64;  // halves
    gl_lds16(gA + k0, dA);
    gl_lds16(gA + k0 + 8 * CH, dA + 8 * 64);
    gl_lds16(gA + k0 + 16 * CH, dA + 16 * 64);
    gl_lds16(gB + k0, dB);
    gl_lds16(gB + k0 + 8 * CH, dB + 8 * 64);
    gl_lds16(gB + k0 + 16 * CH, dB + 16 * 64);
    __syncthreads();
#pragma unroll
    for (int ks = 0; ks < 2; ++ks) {
      const int kb = ks * 4 + g;
      bf8_t af[6], bf_[3];
#pragma unroll
      for (int mi = 0; mi < 6; ++mi) {
        const int r = wm * 96 + mi * 16 + c;
        af[mi] = *(const bf8_t*)(lA + r * 64 + ((kb ^ (c & 7)) * 8));
      }
#pragma unroll
      for (int ni = 0; ni < 3; ++ni) {
        const int r = wn * 48 + ni * 16 + c;
        bf_[ni] = *(const bf8_t*)(lB + r * 64 + ((kb ^ (c & 7)) * 8));
      }
#pragma unroll
      for (int mi = 0; mi < 6; ++mi)
#pragma unroll
        for (int ni = 0; ni < 3; ++ni)
          acc[mi][ni] = __builtin_amdgcn_mfma_f32_16x16x32_bf16(af[mi], bf_[ni], acc[mi][ni], 0, 0, 0);
    }
    __syncthreads();
  }

  // e = exp(SCALE*acc).  C/D: col(s)=c (+ni*16+wn*48), row(q)=g*4+r (+mi*16+wm*96)
#pragma unroll
  for (int mi = 0; mi < 6; ++mi)
#pragma unroll
    for (int ni = 0; ni < 3; ++ni)
#pragma unroll
      for (int r = 0; r < 4; ++r)
        acc[mi][ni][r] = __expf(acc[mi][ni][r] * SCALE);

  if (!FULL) {
#pragma unroll
    for (int mi = 0; mi < 6; ++mi)
#pragma unroll
      for (int r = 0; r < 4; ++r) {
        float v = acc[mi][0][r] + acc[mi][1][r] + acc[mi][2][r];
        v += __shfl_xor(v, 1, 64);
        v += __shfl_xor(v, 2, 64);
        v += __shfl_xor(v, 4, 64);
        v += __shfl_xor(v, 8, 64);
        if (c == 0) atomicAdd(&rowsum[n * HW + Q0 + wm * 96 + mi * 16 + g * 4 + r], v);
      }
#pragma unroll
    for (int ni = 0; ni < 3; ++ni) {
      float v = 0.f;
#pragma unroll
      for (int mi = 0; mi < 6; ++mi)
#pragma unroll
        for (int r = 0; r < 4; ++r) v += acc[mi][ni][r];
      v += __shfl_xor(v, 16, 64);
      v += __shfl_xor(v, 32, 64);
      if (g == 0) atomicAdd(&colsum[n * HW + S0 + wn * 48 + ni * 16 + c], v);
    }
    return;
  }

  // ---- FULL epilogue: stream tiles through LDS, wide stores ----
  float icv[3];
#pragma unroll
  for (int ni = 0; ni < 3; ++ni) icv[ni] = invc[n * HW + S0 + wn * 48 + ni * 16 + c];

  float* fb = (float*)smem;  // 48 x 196 floats = 37.6 KB (reuse of lA/lB)
  const int hq = blockIdx.y, bx = blockIdx.x;

  // pi tile (out1 rows q, out5 remapped rows), 4 chunks of 48 q-rows
#pragma unroll
  for (int ch = 0; ch < 4; ++ch) {
    if (wm == (ch >> 1)) {
#pragma unroll
      for (int m3 = 0; m3 < 3; ++m3) {
        const int mi = (ch & 1) * 3 + m3;
        const int rowb = m3 * 16 + g * 4;
#pragma unroll
        for (int ni = 0; ni < 3; ++ni) {
          const int colb = wn * 48 + ni * 16 + c;
#pragma unroll
          for (int r = 0; r < 4; ++r)
            fb[(rowb + r) * 196 + colb] = acc[mi][ni][r] * icv[ni];
        }
      }
    }
    __syncthreads();
#pragma unroll
    for (int j = 0; j < 5; ++j) {
      const int idx = t + j * 512;
      if (idx < 2304) {
        const int row = idx / 48, col4 = idx % 48;
        const float4 v = *(const float4*)(fb + row * 196 + col4 * 4);
        *(float4*)(out1 + ((size_t)n * HW + Q0 + ch * 48 + row) * HW + S0 + col4 * 4) = v;
        const size_t r5 = ((size_t)n * 144 + hq * 12 + (row >> 2)) * 16 + ch * 4 + (row & 3);
        *(float4*)(out5 + r5 * HW + S0 + col4 * 4) = v;
      }
    }
    __syncthreads();
  }

  // pq tile (out2 rows s, out6 remapped rows), 4 chunks of 48 s-rows (= wn)
#pragma unroll
  for (int ch = 0; ch < 4; ++ch) {
    if (wn == ch) {
#pragma unroll
      for (int mi = 0; mi < 6; ++mi) {
        const int colf = wm * 96 + mi * 16 + g * 4;
        const f32x4 irv = *(const f32x4*)(invr + n * HW + Q0 + colf);
#pragma unroll
        for (int ni = 0; ni < 3; ++ni) {
          const f32x4 pq = acc[mi][ni] * irv;
          *(f32x4*)(fb + (ni * 16 + c) * 196 + colf) = pq;
        }
      }
    }
    __syncthreads();
#pragma unroll
    for (int j = 0; j < 5; ++j) {
      const int idx = t + j * 512;
      if (idx < 2304) {
        const int row = idx / 48, col4 = idx % 48;
        const float4 v = *(const float4*)(fb + row * 196 + col4 * 4);
        *(float4*)(out2 + ((size_t)n * HW + S0 + ch * 48 + row) * HW + Q0 + col4 * 4) = v;
        const size_t r6 = ((size_t)n * 144 + bx * 12 + (row >> 2)) * 16 + ch * 4 + (row & 3);
        *(float4*)(out6 + r6 * HW + Q0 + col4 * 4) = v;
      }
    }
    __syncthreads();
  }

  // out3 (instance_d): per-thread patch partials, combine wm halves in LDS
#pragma unroll
  for (int m3 = 0; m3 < 3; ++m3) {
    const int b = m3 * 4 + g;  // q-patch col 0..11
#pragma unroll
    for (int ni = 0; ni < 3; ++ni) {
      const int sl = wn * 48 + ni * 16 + c;
      float p = 0.f;
#pragma unroll
      for (int r = 0; r < 4; ++r) p += acc[m3][ni][r] + acc[m3 + 3][ni][r];
      fb[(wm * 12 + b) * 196 + sl] = p * icv[ni];
    }
  }
  __syncthreads();
#pragma unroll
  for (int j = 0; j < 5; ++j) {
    const int idx = t + j * 512;
    if (idx < 2304) {
      const int b = idx / 192, sl = idx % 192;
      const float v = fb[b * 196 + sl] + fb[(12 + b) * 196 + sl];
      out3[((size_t)n * 144 + hq * 12 + b) * HW + S0 + sl] = fminf(v, EPSC);
    }
  }
  __syncthreads();

  // out4 (query_d): shfl-reduce 4 s-lanes, combine 4 wn waves in LDS
#pragma unroll
  for (int mi = 0; mi < 6; ++mi) {
    const int qloc = wm * 96 + mi * 16 + g * 4;
    const f32x4 irv = *(const f32x4*)(invr + n * HW + Q0 + qloc);
#pragma unroll
    for (int ni = 0; ni < 3; ++ni) {
      f32x4 pq = acc[mi][ni] * irv;
#pragma unroll
      for (int r = 0; r < 4; ++r) {
        pq[r] += __shfl_xor(pq[r], 1, 64);
        pq[r] += __shfl_xor(pq[r], 2, 64);
      }
      if ((c & 3) == 0) {
        const int pc = ni * 4 + (c >> 2);  // s-patch col 0..11
        *(f32x4*)(fb + (wn * 12 + pc) * 196 + qloc) = pq;
      }
    }
  }
  __syncthreads();
#pragma unroll
  for (int j = 0; j < 5; ++j) {
    const int idx = t + j * 512;
    if (idx < 2304) {
      const int pc = idx / 192, q = idx % 192;
      const float v = fb[pc * 196 + q] + fb[(12 + pc) * 196 + q] +
                      fb[(24 + pc) * 196 + q] + fb[(36 + pc) * 196 + q];
      out4[((size_t)n * 144 + bx * 12 + pc) * HW + Q0 + q] = fminf(v, EPSC);
    }
  }
}

// ===========================================================================
// Fallback path (ws too small): old validated kernels
// ===========================================================================
__global__ __launch_bounds__(256) void k_gemm_old(const unsigned short* __restrict__ Abf,
                                                  const unsigned short* __restrict__ Bbf,
                                                  float* __restrict__ out1,
                                                  float* __restrict__ rowsum,
                                                  float* __restrict__ colsum) {
  __shared__ unsigned short lA[128 * 64];
  __shared__ unsigned short lB[128 * 64];
  const int n = blockIdx.z;
  const int s0 = blockIdx.x * 128, q0 = blockIdx.y * 128;
  const int t = threadIdx.x, l = t & 63, w = t >> 6;
  const int wm = w >> 1, wn = w & 1;
  f32x4 acc[4][4];
#pragma unroll
  for (int mi = 0; mi < 4; ++mi)
#pragma unroll
    for (int ni = 0; ni < 4; ++ni) {
      f32x4 z = {0.f, 0.f, 0.f, 0.f};
      acc[mi][ni] = z;
    }
  const size_t baseA = ((size_t)n * HW + q0) * CH;
  const size_t baseB = ((size_t)n * HW + s0) * CH;
  const int jj = t & 7, rr = t >> 3;
  for (int kc = 0; kc < 4; ++kc) {
    const int k0 = kc * 64;
#pragma unroll
    for (int i = 0; i < 4; ++i) {
      const int r = i * 32 + rr;
      bf8_t va = *(const bf8_t*)(Abf + baseA + (size_t)r * CH + k0 + jj * 8);
      bf8_t vb = *(const bf8_t*)(Bbf + baseB + (size_t)r * CH + k0 + jj * 8);
      *(bf8_t*)(lA + r * 64 + ((jj ^ (r & 7)) * 8)) = va;
      *(bf8_t*)(lB + r * 64 + ((jj ^ (r & 7)) * 8)) = vb;
    }
    __syncthreads();
#pragma unroll
    for (int ks = 0; ks < 2; ++ks) {
      const int kb = ks * 4 + (l >> 4);
      bf8_t af[4], bfr[4];
#pragma unroll
      for (int mi = 0; mi < 4; ++mi) {
        const int r = wm * 64 + mi * 16 + (l & 15);
        af[mi] = *(const bf8_t*)(lA + r * 64 + ((kb ^ (r & 7)) * 8));
      }
#pragma unroll
      for (int ni = 0; ni < 4; ++ni) {
        const int r = wn * 64 + ni * 16 + (l & 15);
        bfr[ni] = *(const bf8_t*)(lB + r * 64 + ((kb ^ (r & 7)) * 8));
      }
#pragma unroll
      for (int mi = 0; mi < 4; ++mi)
#pragma unroll
        for (int ni = 0; ni < 4; ++ni)
          acc[mi][ni] = __builtin_amdgcn_mfma_f32_16x16x32_bf16(af[mi], bfr[ni], acc[mi][ni], 0, 0, 0);
    }
    __syncthreads();
  }
  float rp[4][4], cp[4];
#pragma unroll
  for (int mi = 0; mi < 4; ++mi)
#pragma unroll
    for (int r = 0; r < 4; ++r) rp[mi][r] = 0.f;
#pragma unroll
  for (int ni = 0; ni < 4; ++ni) cp[ni] = 0.f;
#pragma unroll
  for (int mi = 0; mi < 4; ++mi) {
    const int row = q0 + wm * 64 + mi * 16 + (l >> 4) * 4;
#pragma unroll
    for (int ni = 0; ni < 4; ++ni) {
      const int col = s0 + wn * 64 + ni * 16 + (l & 15);
      const size_t ob = ((size_t)n * HW + row) * HW + col;
#pragma unroll
      for (int r = 0; r < 4; ++r) {
        const float e = __expf(acc[mi][ni][r] * SCALE);
        out1[ob + (size_t)r * HW] = e;
        rp[mi][r] += e;
        cp[ni] += e;
      }
    }
  }
#pragma unroll
  for (int mi = 0; mi < 4; ++mi)
#pragma unroll
    for (int r = 0; r < 4; ++r) {
      float v = rp[mi][r];
      v += __shfl_xor(v, 1, 64);
      v += __shfl_xor(v, 2, 64);
      v += __shfl_xor(v, 4, 64);
      v += __shfl_xor(v, 8, 64);
      if ((l & 15) == 0)
        atomicAdd(&rowsum[n * HW + q0 + wm * 64 + mi * 16 + (l >> 4) * 4 + r], v);
    }
#pragma unroll
  for (int ni = 0; ni < 4; ++ni) {
    float v = cp[ni];
    v += __shfl_xor(v, 16, 64);
    v += __shfl_xor(v, 32, 64);
    if (l < 16) atomicAdd(&colsum[n * HW + s0 + wn * 64 + ni * 16 + l], v);
  }
}

__global__ __launch_bounds__(192) void k_main(float* __restrict__ out1,
                                              float* __restrict__ out2,
                                              float* __restrict__ out3,
                                              float* __restrict__ out5,
                                              float* __restrict__ out6,
                                              const float* __restrict__ invr,
                                              const float* __restrict__ invc) {
  __shared__ float ldsT[192 * 49];
  const int n = blockIdx.z, h = blockIdx.y, sb = blockIdx.x;
  const int S0 = sb * 192;
  const int t = threadIdx.x;
  const int sg = S0 + t;
  const float icv = invc[n * HW + sg];
  const float* invr_n = invr + n * HW;
  float* e_base = out1 + (size_t)n * SZ_QS;
  const int Q0 = h * 192;
  float acc[12];
#pragma unroll
  for (int i = 0; i < 12; ++i) acc[i] = 0.f;
  for (int ph = 0; ph < 4; ++ph) {
    const int qf0 = Q0 + ph * 48;
#pragma unroll
    for (int wi = 0; wi < 12; ++wi) {
#pragma unroll
      for (int pw = 0; pw < 4; ++pw) {
        const int col = wi * 4 + pw;
        const int q = qf0 + col;
        const size_t eoff = (size_t)q * HW + sg;
        const float e = e_base[eoff];
        const float pi = e * icv;
        e_base[eoff] = pi;
        out5[((size_t)((n * 144 + h * 12 + wi) * 16 + (ph * 4 + pw))) * HW + sg] = pi;
        acc[wi] += pi;
        ldsT[t * 49 + col] = e * invr_n[q];
      }
    }
    __syncthreads();
    const int u = t & 3, sB = t >> 2;
#pragma unroll
    for (int pass = 0; pass < 4; ++pass) {
      const int sl = pass * 48 + sB;
      const int sgl = S0 + sl;
      const int rs_ = sgl / 48, cs = sgl % 48;
      const int sp = (rs_ >> 2) * 12 + (cs >> 2);
      const int spp = (rs_ & 3) * 4 + (cs & 3);
      const size_t o2row = ((size_t)n * HW + sgl) * HW + qf0;
      const size_t o6row = (((size_t)n * 144 + sp) * 16 + spp) * HW + qf0;
#pragma unroll
      for (int k = 0; k < 3; ++k) {
        const int slot = u + k * 4;
        float4 v;
        v.x = ldsT[sl * 49 + slot * 4 + 0];
        v.y = ldsT[sl * 49 + slot * 4 + 1];
        v.z = ldsT[sl * 49 + slot * 4 + 2];
        v.w = ldsT[sl * 49 + slot * 4 + 3];
        *(float4*)(out2 + o2row + slot * 4) = v;
        *(float4*)(out6 + o6row + slot * 4) = v;
      }
    }
    __syncthreads();
  }
#pragma unroll
  for (int wi = 0; wi < 12; ++wi)
    out3[((size_t)(n * 144 + h * 12 + wi)) * HW + sg] = fminf(acc[wi], EPSC);
}

__global__ __launch_bounds__(256) void k_qd(const float* __restrict__ out6,
                                            float* __restrict__ out4) {
  const int n = blockIdx.y, sp = blockIdx.x;
  const float* b6 = out6 + (((size_t)n * 144 + sp) * 16) * HW;
  float* b4 = out4 + ((size_t)n * 144 + sp) * HW;
  for (int i = 0; i < 9; ++i) {
    const int qq = i * 256 + threadIdx.x;
    float s = 0.f;
#pragma unroll
    for (int spp = 0; spp < 16; ++spp) s += b6[(size_t)spp * HW + qq];
    b4[qq] = fminf(s, EPSC);
  }
}

// ---------------------------------------------------------------------------
extern "C" void kernel_launch(void* const* d_in, const int* in_sizes, int n_in,
                              void* d_out, int out_size, void* d_ws, size_t ws_size,
                              hipStream_t stream) {
  const float* mask_f = (const float*)d_in[0];
  const float* query_f = (const float*)d_in[1];
  float* out = (float*)d_out;
  float* out1 = out + O1;
  float* out2 = out + O2;
  float* out3 = out + O3;
  float* out4 = out + O4;
  float* out5 = out + O5;
  float* out6 = out + O6;

  const size_t abytes = (size_t)N_B * HW * CH * 2;  // 9,437,184 per operand
  const size_t sbytes = (size_t)N_B * HW * 4;       // 73,728 per sum array
  const size_t need = 2 * abytes + 4 * sbytes;

  if (ws_size >= need) {
    char* base = (char*)d_ws;
    __hip_bfloat16* Abf = (__hip_bfloat16*)base;
    __hip_bfloat16* Bbf = (__hip_bfloat16*)(base + abytes);
    float* sums = (float*)(base + 2 * abytes);
    float* invs = (float*)(base + 2 * abytes + 2 * sbytes);
    float* rowsum = sums;
    float* colsum = sums + N_B * HW;
    float* invr = invs;
    float* invc = invs + N_B * HW;

    k_tr<<<dim3(36, 4, 16), 256, 0, stream>>>(query_f, mask_f, Abf, Bbf);
    k_zero<<<dim3(36), 256, 0, stream>>>(sums);
    k_g192<0><<<dim3(12, 12, 8), 512, 0, stream>>>(
        (const unsigned short*)Abf, (const unsigned short*)Bbf,
        nullptr, nullptr, nullptr, nullptr, nullptr, nullptr,
        rowsum, colsum, nullptr, nullptr);
    k_inv<<<dim3(144), 256, 0, stream>>>(sums, invs);
    k_g192<1><<<dim3(12, 12, 8), 512, 0, stream>>>(
        (const unsigned short*)Abf, (const unsigned short*)Bbf,
        out1, out2, out3, out4, out5, out6,
        nullptr, nullptr, invr, invc);
  } else {
    // Fallback: scratch carved from out regions; old validated 3-kernel path.
    __hip_bfloat16* Abf = (__hip_bfloat16*)out4;
    __hip_bfloat16* Bbf = (__hip_bfloat16*)out3;
    float* sums = (float*)((char*)out4 + abytes);
    float* invs = sums + 2 * (N_B * HW);
    float* rowsum = sums;
    float* colsum = sums + N_B * HW;
    float* invr = invs;
    float* invc = invs + N_B * HW;

    k_tr<<<dim3(36, 4, 16), 256, 0, stream>>>(query_f, mask_f, Abf, Bbf);
    k_zero<<<dim3(36), 256, 0, stream>>>(sums);
    k_gemm_old<<<dim3(18, 18, 8), 256, 0, stream>>>(
        (const unsigned short*)Abf, (const unsigned short*)Bbf, out1, rowsum, colsum);
    k_inv<<<dim3(144), 256, 0, stream>>>(sums, invs);
    k_main<<<dim3(12, 12, 8), 192, 0, stream>>>(out1, out2, out3, out5, out6, invr, invc);
    k_qd<<<dim3(144, 8), 256, 0, stream>>>(out6, out4);
  }
}